// Round 2
// baseline (99.242 us; speedup 1.0000x reference)
//
#include <hip/hip_runtime.h>
#include <hip/hip_bf16.h>

#define B_ROWS 4096
#define N_ROWS 8192
#define D 128
#define SCALE 2.885390081777927f   // (1/temperature) * log2(e) = 2 * 1.4426950408889634
#define LN2 0.6931471805599453f

#define RB 256        // rows per block = 4 waves x 64 rows
#define CSPLIT 512    // columns swept per block
#define CHUNK 64      // columns staged in LDS per pass
#define NCHUNK (CSPLIT / CHUNK)

typedef __attribute__((ext_vector_type(8))) short bf16x8;
typedef __attribute__((ext_vector_type(4))) float f32x4;

__device__ inline unsigned short f32_to_bf16_rne(float f) {
    unsigned int u = __float_as_uint(f);
    u += 0x7fffu + ((u >> 16) & 1u);   // round-to-nearest-even (no NaNs here)
    return (unsigned short)(u >> 16);
}
__device__ inline float bf16s_to_f32(short s) {
    unsigned int u = ((unsigned int)(unsigned short)s) << 16;
    return __uint_as_float(u);
}

// ---------------- Kernel 1: row-normalize fp32 -> bf16 ----------------
// 256-thread blocks, one wave per row, 4 rows/block.
__global__ void k_normalize(const float* __restrict__ z_i,
                            const float* __restrict__ z_j,
                            unsigned short* __restrict__ zn) {
    int row  = blockIdx.x * 4 + (threadIdx.x >> 6);
    int lane = threadIdx.x & 63;
    const float* src = (row < B_ROWS) ? (z_i + (size_t)row * D)
                                      : (z_j + (size_t)(row - B_ROWS) * D);
    float2 v = ((const float2*)src)[lane];
    float ss = v.x * v.x + v.y * v.y;
    #pragma unroll
    for (int m = 1; m < 64; m <<= 1) ss += __shfl_xor(ss, m);
    float rinv = 1.0f / fmaxf(sqrtf(ss), 1e-8f);
    ushort2 o;
    o.x = f32_to_bf16_rne(v.x * rinv);
    o.y = f32_to_bf16_rne(v.y * rinv);
    ((ushort2*)(zn + (size_t)row * D))[lane] = o;
}

// ---------------- Kernel 2: fused sim-GEMM + exp + row-sum ----------------
// grid = (N/RB, N/CSPLIT) = (32, 16), block = 256 (4 waves).
// Wave w owns 64 rows (4 x 16-row MFMA tiles); A fragments live in registers.
// B chunks (64 zn rows) staged in LDS with XOR-swizzled 16B-piece layout:
//   piece(c, j) stored at index c*16 + (j ^ (c & 7)), j = 16B-chunk within row.
// This makes both staging writes and fragment reads bank-conflict-free.
__global__ __launch_bounds__(256, 2)
void k_simsum(const unsigned short* __restrict__ zn,
              float* __restrict__ denom) {
    __shared__ unsigned short sB[2 * CHUNK * 16 * 8];   // 2 x 16 KB
    const int tid  = threadIdx.x;
    const int wave = tid >> 6;
    const int lane = tid & 63;
    const int l15  = lane & 15;
    const int quad = lane >> 4;
    const int m0   = blockIdx.x * RB + wave * 64;

    // A fragments: 4 row-tiles x 4 k-blocks, kept in registers for the sweep.
    // frag[j] = zn[row][kb*32 + quad*8 + j]  (A and B layouts coincide for X*X^T)
    bf16x8 A[4][4];
    #pragma unroll
    for (int rt = 0; rt < 4; ++rt)
        #pragma unroll
        for (int kb = 0; kb < 4; ++kb)
            A[rt][kb] = *(const bf16x8*)(zn + (size_t)(m0 + rt * 16 + l15) * D + kb * 32 + quad * 8);

    float rs[4][4];
    #pragma unroll
    for (int rt = 0; rt < 4; ++rt)
        #pragma unroll
        for (int j = 0; j < 4; ++j) rs[rt][j] = 0.f;

    const int c_base = blockIdx.y * CSPLIT;

    // prefetch chunk 0 into registers
    float4 st[4];
    #pragma unroll
    for (int p = 0; p < 4; ++p) {
        int i = tid + p * 256, c = i >> 4, j = i & 15;
        st[p] = *(const float4*)(zn + (size_t)(c_base + c) * D + j * 8);
    }

    for (int cb = 0; cb < NCHUNK; ++cb) {
        unsigned short* buf = sB + (cb & 1) * (CHUNK * 16 * 8);
        // commit staged registers -> LDS (swizzled)
        #pragma unroll
        for (int p = 0; p < 4; ++p) {
            int i = tid + p * 256, c = i >> 4, j = i & 15;
            int piece = c * 16 + (j ^ (c & 7));
            *(float4*)(buf + piece * 8) = st[p];
        }
        __syncthreads();   // one barrier per chunk (double-buffered)

        // prefetch next chunk while computing this one
        if (cb + 1 < NCHUNK) {
            #pragma unroll
            for (int p = 0; p < 4; ++p) {
                int i = tid + p * 256, c = i >> 4, j = i & 15;
                st[p] = *(const float4*)(zn + (size_t)(c_base + (cb + 1) * CHUNK + c) * D + j * 8);
            }
        }

        #pragma unroll
        for (int t = 0; t < 4; ++t) {           // 4 col-tiles of 16 per chunk
            bf16x8 b[4];
            #pragma unroll
            for (int kb = 0; kb < 4; ++kb) {
                int c = t * 16 + l15;
                int piece = c * 16 + ((kb * 4 + quad) ^ (c & 7));
                b[kb] = *(const bf16x8*)(buf + piece * 8);
            }
            f32x4 acc[4];
            #pragma unroll
            for (int rt = 0; rt < 4; ++rt) acc[rt] = (f32x4){0.f, 0.f, 0.f, 0.f};
            #pragma unroll
            for (int kb = 0; kb < 4; ++kb)
                #pragma unroll
                for (int rt = 0; rt < 4; ++rt)
                    acc[rt] = __builtin_amdgcn_mfma_f32_16x16x32_bf16(A[rt][kb], b[kb], acc[rt], 0, 0, 0);
            #pragma unroll
            for (int rt = 0; rt < 4; ++rt)
                #pragma unroll
                for (int j = 0; j < 4; ++j)
                    rs[rt][j] += __builtin_amdgcn_exp2f(acc[rt][j] * SCALE);
        }
    }

    // rs[rt][j]: partial row-sum for row m0+rt*16+quad*4+j over cols == l15 (mod 16)
    #pragma unroll
    for (int rt = 0; rt < 4; ++rt)
        #pragma unroll
        for (int j = 0; j < 4; ++j) {
            float v = rs[rt][j];
            v += __shfl_xor(v, 1);
            v += __shfl_xor(v, 2);
            v += __shfl_xor(v, 4);
            v += __shfl_xor(v, 8);
            rs[rt][j] = v;
        }
    if (l15 == 0) {
        #pragma unroll
        for (int rt = 0; rt < 4; ++rt)
            #pragma unroll
            for (int j = 0; j < 4; ++j)
                atomicAdd(&denom[m0 + rt * 16 + quad * 4 + j], rs[rt][j]);
    }
}

// ---------------- Kernel 3: per-row loss + mean reduce ----------------
__global__ void k_finalize(const unsigned short* __restrict__ zn,
                           const float* __restrict__ denom,
                           float* __restrict__ out) {
    int i = blockIdx.x * blockDim.x + threadIdx.x;
    int p = (i + B_ROWS) & (N_ROWS - 1);
    const unsigned short* zi = zn + (size_t)i * D;
    const unsigned short* zp = zn + (size_t)p * D;
    float self_dot = 0.f, pos_dot = 0.f;
    #pragma unroll
    for (int c = 0; c < D / 8; ++c) {
        bf16x8 a = *(const bf16x8*)(zi + c * 8);
        bf16x8 b = *(const bf16x8*)(zp + c * 8);
        #pragma unroll
        for (int j = 0; j < 8; ++j) {
            float av = bf16s_to_f32(a[j]);
            float bv = bf16s_to_f32(b[j]);
            self_dot += av * av;
            pos_dot  += av * bv;
        }
    }
    // denom included self and pos terms; subtract self (same exp2 arithmetic).
    float dnm  = denom[i] - __builtin_amdgcn_exp2f(self_dot * SCALE);
    float loss = __builtin_amdgcn_logf(dnm) * LN2 - pos_dot * 2.0f;  // log(exp(s)/D) form

    float v = loss;
    #pragma unroll
    for (int m = 1; m < 64; m <<= 1) v += __shfl_xor(v, m);
    __shared__ float ws[4];
    int wave = threadIdx.x >> 6;
    if ((threadIdx.x & 63) == 0) ws[wave] = v;
    __syncthreads();
    if (threadIdx.x == 0) {
        float s = ws[0] + ws[1] + ws[2] + ws[3];
        atomicAdd(out, s * (1.0f / (float)N_ROWS));
    }
}

extern "C" void kernel_launch(void* const* d_in, const int* in_sizes, int n_in,
                              void* d_out, int out_size, void* d_ws, size_t ws_size,
                              hipStream_t stream) {
    const float* z_i = (const float*)d_in[0];
    const float* z_j = (const float*)d_in[1];
    float* out = (float*)d_out;

    unsigned short* zn = (unsigned short*)d_ws;                      // N*D bf16 = 2 MB
    float* denom = (float*)((char*)d_ws + (size_t)N_ROWS * D * 2);   // N fp32 = 32 KB

    hipMemsetAsync(denom, 0, N_ROWS * sizeof(float), stream);
    hipMemsetAsync(out, 0, sizeof(float), stream);

    k_normalize<<<N_ROWS / 4, 256, 0, stream>>>(z_i, z_j, zn);
    k_simsum<<<dim3(N_ROWS / RB, N_ROWS / CSPLIT), 256, 0, stream>>>(zn, denom);
    k_finalize<<<N_ROWS / 256, 256, 0, stream>>>(zn, denom, out);
}

// Round 3
// 94.175 us; speedup vs baseline: 1.0538x; 1.0538x over previous
//
#include <hip/hip_runtime.h>
#include <hip/hip_bf16.h>

#define B_ROWS 4096
#define N_ROWS 8192
#define D 128
#define SCALE 2.885390081777927f   // (1/temperature) * log2(e) = 2 * 1.4426950408889634
#define LN2 0.6931471805599453f

#define RB 256        // rows per block = 4 waves x 64 rows
#define CSPLIT 512    // columns swept per block
#define CHUNK 64      // columns staged in LDS per pass
#define NCHUNK (CSPLIT / CHUNK)

typedef __attribute__((ext_vector_type(8))) short bf16x8;
typedef __attribute__((ext_vector_type(4))) float f32x4;

__device__ inline unsigned short f32_to_bf16_rne(float f) {
    unsigned int u = __float_as_uint(f);
    u += 0x7fffu + ((u >> 16) & 1u);   // round-to-nearest-even (no NaNs here)
    return (unsigned short)(u >> 16);
}
__device__ inline float bf16s_to_f32(short s) {
    unsigned int u = ((unsigned int)(unsigned short)s) << 16;
    return __uint_as_float(u);
}

// ---------------- Kernel 1: row-normalize fp32 -> bf16 (+ zero denom/out) ----
// 256-thread blocks, one wave per row, 4 rows/block. First 32 blocks also
// zero the denominator array; block 0 zeroes the scalar output. Stream order
// makes these visible to k_simsum / k_finalize — no memset nodes needed.
__global__ void k_normalize(const float* __restrict__ z_i,
                            const float* __restrict__ z_j,
                            unsigned short* __restrict__ zn,
                            float* __restrict__ denom,
                            float* __restrict__ out) {
    if (blockIdx.x < 32) denom[blockIdx.x * 256 + threadIdx.x] = 0.f;
    if (blockIdx.x == 0 && threadIdx.x == 0) out[0] = 0.f;

    int row  = blockIdx.x * 4 + (threadIdx.x >> 6);
    int lane = threadIdx.x & 63;
    const float* src = (row < B_ROWS) ? (z_i + (size_t)row * D)
                                      : (z_j + (size_t)(row - B_ROWS) * D);
    float2 v = ((const float2*)src)[lane];
    float ss = v.x * v.x + v.y * v.y;
    #pragma unroll
    for (int m = 1; m < 64; m <<= 1) ss += __shfl_xor(ss, m);
    float rinv = 1.0f / fmaxf(sqrtf(ss), 1e-8f);
    ushort2 o;
    o.x = f32_to_bf16_rne(v.x * rinv);
    o.y = f32_to_bf16_rne(v.y * rinv);
    ((ushort2*)(zn + (size_t)row * D))[lane] = o;
}

// ---------------- Kernel 2: fused sim-GEMM + exp + row-sum ----------------
// grid = (N/RB, N/CSPLIT) = (32, 16), block = 256 (4 waves).
// Wave w owns 64 rows (4 x 16-row MFMA tiles); A fragments live in registers.
// B chunks (64 zn rows) staged in LDS with XOR-swizzled 16B-piece layout:
//   piece(c, j) stored at index c*16 + (j ^ (c & 7)), j = 16B-chunk within row.
__global__ __launch_bounds__(256, 2)
void k_simsum(const unsigned short* __restrict__ zn,
              float* __restrict__ denom) {
    __shared__ unsigned short sB[2 * CHUNK * 16 * 8];   // 2 x 16 KB
    const int tid  = threadIdx.x;
    const int wave = tid >> 6;
    const int lane = tid & 63;
    const int l15  = lane & 15;
    const int quad = lane >> 4;
    const int m0   = blockIdx.x * RB + wave * 64;

    // A fragments: 4 row-tiles x 4 k-blocks, kept in registers for the sweep.
    // frag[j] = zn[row][kb*32 + quad*8 + j]  (A and B layouts coincide for X*X^T)
    bf16x8 A[4][4];
    #pragma unroll
    for (int rt = 0; rt < 4; ++rt)
        #pragma unroll
        for (int kb = 0; kb < 4; ++kb)
            A[rt][kb] = *(const bf16x8*)(zn + (size_t)(m0 + rt * 16 + l15) * D + kb * 32 + quad * 8);

    float rs[4][4];
    #pragma unroll
    for (int rt = 0; rt < 4; ++rt)
        #pragma unroll
        for (int j = 0; j < 4; ++j) rs[rt][j] = 0.f;

    const int c_base = blockIdx.y * CSPLIT;

    // prefetch chunk 0 into registers
    float4 st[4];
    #pragma unroll
    for (int p = 0; p < 4; ++p) {
        int i = tid + p * 256, c = i >> 4, j = i & 15;
        st[p] = *(const float4*)(zn + (size_t)(c_base + c) * D + j * 8);
    }

    for (int cb = 0; cb < NCHUNK; ++cb) {
        unsigned short* buf = sB + (cb & 1) * (CHUNK * 16 * 8);
        // commit staged registers -> LDS (swizzled)
        #pragma unroll
        for (int p = 0; p < 4; ++p) {
            int i = tid + p * 256, c = i >> 4, j = i & 15;
            int piece = c * 16 + (j ^ (c & 7));
            *(float4*)(buf + piece * 8) = st[p];
        }
        __syncthreads();   // one barrier per chunk (double-buffered)

        // prefetch next chunk while computing this one
        if (cb + 1 < NCHUNK) {
            #pragma unroll
            for (int p = 0; p < 4; ++p) {
                int i = tid + p * 256, c = i >> 4, j = i & 15;
                st[p] = *(const float4*)(zn + (size_t)(c_base + (cb + 1) * CHUNK + c) * D + j * 8);
            }
        }

        #pragma unroll
        for (int t = 0; t < 4; ++t) {           // 4 col-tiles of 16 per chunk
            bf16x8 b[4];
            #pragma unroll
            for (int kb = 0; kb < 4; ++kb) {
                int c = t * 16 + l15;
                int piece = c * 16 + ((kb * 4 + quad) ^ (c & 7));
                b[kb] = *(const bf16x8*)(buf + piece * 8);
            }
            f32x4 acc[4];
            #pragma unroll
            for (int rt = 0; rt < 4; ++rt) acc[rt] = (f32x4){0.f, 0.f, 0.f, 0.f};
            #pragma unroll
            for (int kb = 0; kb < 4; ++kb)
                #pragma unroll
                for (int rt = 0; rt < 4; ++rt)
                    acc[rt] = __builtin_amdgcn_mfma_f32_16x16x32_bf16(A[rt][kb], b[kb], acc[rt], 0, 0, 0);
            #pragma unroll
            for (int rt = 0; rt < 4; ++rt)
                #pragma unroll
                for (int j = 0; j < 4; ++j)
                    rs[rt][j] += __builtin_amdgcn_exp2f(acc[rt][j] * SCALE);
        }
    }

    // rs[rt][j]: partial row-sum for row m0+rt*16+quad*4+j over cols == l15 (mod 16)
    #pragma unroll
    for (int rt = 0; rt < 4; ++rt)
        #pragma unroll
        for (int j = 0; j < 4; ++j) {
            float v = rs[rt][j];
            v += __shfl_xor(v, 1);
            v += __shfl_xor(v, 2);
            v += __shfl_xor(v, 4);
            v += __shfl_xor(v, 8);
            rs[rt][j] = v;
        }
    if (l15 == 0) {
        #pragma unroll
        for (int rt = 0; rt < 4; ++rt)
            #pragma unroll
            for (int j = 0; j < 4; ++j)
                atomicAdd(&denom[m0 + rt * 16 + quad * 4 + j], rs[rt][j]);
    }
}

// ---------------- Kernel 3: per-row loss + mean reduce ----------------
__global__ void k_finalize(const unsigned short* __restrict__ zn,
                           const float* __restrict__ denom,
                           float* __restrict__ out) {
    int i = blockIdx.x * blockDim.x + threadIdx.x;
    int p = (i + B_ROWS) & (N_ROWS - 1);
    const unsigned short* zi = zn + (size_t)i * D;
    const unsigned short* zp = zn + (size_t)p * D;
    float self_dot = 0.f, pos_dot = 0.f;
    #pragma unroll
    for (int c = 0; c < D / 8; ++c) {
        bf16x8 a = *(const bf16x8*)(zi + c * 8);
        bf16x8 b = *(const bf16x8*)(zp + c * 8);
        #pragma unroll
        for (int j = 0; j < 8; ++j) {
            float av = bf16s_to_f32(a[j]);
            float bv = bf16s_to_f32(b[j]);
            self_dot += av * av;
            pos_dot  += av * bv;
        }
    }
    // denom included self and pos terms; subtract self (same exp2 arithmetic).
    float dnm  = denom[i] - __builtin_amdgcn_exp2f(self_dot * SCALE);
    float loss = __builtin_amdgcn_logf(dnm) * LN2 - pos_dot * 2.0f;  // -log(pos/denom)

    float v = loss;
    #pragma unroll
    for (int m = 1; m < 64; m <<= 1) v += __shfl_xor(v, m);
    __shared__ float ws[4];
    int wave = threadIdx.x >> 6;
    if ((threadIdx.x & 63) == 0) ws[wave] = v;
    __syncthreads();
    if (threadIdx.x == 0) {
        float s = ws[0] + ws[1] + ws[2] + ws[3];
        atomicAdd(out, s * (1.0f / (float)N_ROWS));
    }
}

extern "C" void kernel_launch(void* const* d_in, const int* in_sizes, int n_in,
                              void* d_out, int out_size, void* d_ws, size_t ws_size,
                              hipStream_t stream) {
    const float* z_i = (const float*)d_in[0];
    const float* z_j = (const float*)d_in[1];
    float* out = (float*)d_out;

    unsigned short* zn = (unsigned short*)d_ws;                      // N*D bf16 = 2 MB
    float* denom = (float*)((char*)d_ws + (size_t)N_ROWS * D * 2);   // N fp32 = 32 KB

    k_normalize<<<N_ROWS / 4, 256, 0, stream>>>(z_i, z_j, zn, denom, out);
    k_simsum<<<dim3(N_ROWS / RB, N_ROWS / CSPLIT), 256, 0, stream>>>(zn, denom);
    k_finalize<<<N_ROWS / 256, 256, 0, stream>>>(zn, denom, out);
}